// Round 1
// baseline (596.550 us; speedup 1.0000x reference)
//
#include <hip/hip_runtime.h>
#include <math.h>

// CBTree contraction, B=4, L=9, d=256.
// Key algebraic optimization: children are combined BEFORE the matmul
// (linearity of GEMM): gL[p] = sum_b lc[b]*h[4p+b], gR[p] = sum_b rc[b]*h[4p+b]
// h_new[p] = tanh( gL[p] @ Wl.T + gR[p] @ Wr.T + vec[p] )
//          = tanh( [gL|gR] @ [Wl|Wr].T + vec[p] )   -> one GEMM, M=n_par, K=512, N=256
// 4x fewer FLOPs than the reference formulation.

constexpr int BM = 32;
constexpr int BN = 256;   // full N -> A staged exactly once
constexpr int BK = 32;
constexpr int ASTRIDE = BM + 4;   // 36: keeps float4 16B-aligned, breaks bank aliasing
constexpr int BSTRIDE = BN + 4;   // 260

__global__ __launch_bounds__(256) void cbt_level_kernel(
    const float* __restrict__ h,    // children values, (4*M, 256)
    const float* __restrict__ Wl,   // (256, 256) row-major
    const float* __restrict__ Wr,   // (256, 256) row-major
    const float* __restrict__ vec,  // this level's vectors, (M, 256)
    float* __restrict__ out,        // (M, 256)
    int M)
{
    __shared__ float As[BK][ASTRIDE];
    __shared__ float Bs[BK][BSTRIDE];

    const int tid = threadIdx.x;
    const int mBase = blockIdx.x * BM;

    const int tx = tid & 7;    // m-group: rows tx*4 .. tx*4+3
    const int ty = tid >> 3;   // n-group: cols ty*8 .. ty*8+7

    float acc[4][8];
#pragma unroll
    for (int i = 0; i < 4; ++i)
#pragma unroll
        for (int j = 0; j < 8; ++j) acc[i][j] = 0.0f;

    constexpr float C23 = 2.0f / 3.0f;
    constexpr float C13 = 1.0f / 3.0f;

    // staging mapping: thread -> (row = tid>>3, 4-wide k chunk = (tid&7)*4)
    const int s_row = tid >> 3;        // 0..31
    const int s_kk  = (tid & 7) << 2;  // 0,4,...,28

    for (int k0 = 0; k0 < 512; k0 += BK) {
        // ---- global loads into registers (no LDS touched yet) ----
        // A tile: fused child combine. Parent row m uses child rows 4m..4m+3.
        float a_st[4] = {0.f, 0.f, 0.f, 0.f};
        const int m = mBase + s_row;
        if (m < M) {
            const float* hb = h + (size_t)m * 1024;  // 4 children * 256
            if (k0 < 256) {
                // gL = 1*c0 + 2/3*c1 + 1/3*c2  (lc = [1, 2/3, 1/3, 0])
                const int k = k0 + s_kk;
                float4 v0 = *reinterpret_cast<const float4*>(hb + k);
                float4 v1 = *reinterpret_cast<const float4*>(hb + 256 + k);
                float4 v2 = *reinterpret_cast<const float4*>(hb + 512 + k);
                a_st[0] = v0.x + C23 * v1.x + C13 * v2.x;
                a_st[1] = v0.y + C23 * v1.y + C13 * v2.y;
                a_st[2] = v0.z + C23 * v1.z + C13 * v2.z;
                a_st[3] = v0.w + C23 * v1.w + C13 * v2.w;
            } else {
                // gR = 1/3*c1 + 2/3*c2 + 1*c3  (rc = [0, 1/3, 2/3, 1])
                const int k = (k0 - 256) + s_kk;
                float4 v1 = *reinterpret_cast<const float4*>(hb + 256 + k);
                float4 v2 = *reinterpret_cast<const float4*>(hb + 512 + k);
                float4 v3 = *reinterpret_cast<const float4*>(hb + 768 + k);
                a_st[0] = C13 * v1.x + C23 * v2.x + v3.x;
                a_st[1] = C13 * v1.y + C23 * v2.y + v3.y;
                a_st[2] = C13 * v1.z + C23 * v2.z + v3.z;
                a_st[3] = C13 * v1.w + C23 * v2.w + v3.w;
            }
        }

        // B tile: 256 rows x 32 cols of [Wl|Wr]; 8 float4 per thread,
        // rows s_row + 32*i, cols k0'+s_kk..+3  (coalesced 128B per 8 threads)
        const float* Wbase = (k0 < 256) ? (Wl + k0 + s_kk)
                                        : (Wr + (k0 - 256) + s_kk);
        float4 wv[8];
#pragma unroll
        for (int i = 0; i < 8; ++i) {
            const int n = s_row + 32 * i;
            wv[i] = *reinterpret_cast<const float4*>(Wbase + (size_t)n * 256);
        }

        __syncthreads();  // previous iteration's compute done before overwrite

        // ---- write LDS (transposed: [k][m] / [k][n]) ----
#pragma unroll
        for (int j = 0; j < 4; ++j) As[s_kk + j][s_row] = a_st[j];
#pragma unroll
        for (int i = 0; i < 8; ++i) {
            float w_st[4] = {wv[i].x, wv[i].y, wv[i].z, wv[i].w};
#pragma unroll
            for (int j = 0; j < 4; ++j) Bs[s_kk + j][s_row + 32 * i] = w_st[j];
        }

        __syncthreads();

        // ---- compute: 32 k-steps, 4x8 micro-tile ----
#pragma unroll
        for (int kk = 0; kk < BK; ++kk) {
            const float4 a4  = *reinterpret_cast<const float4*>(&As[kk][tx << 2]);
            const float4 b4a = *reinterpret_cast<const float4*>(&Bs[kk][ty << 3]);
            const float4 b4b = *reinterpret_cast<const float4*>(&Bs[kk][(ty << 3) + 4]);
            const float a[4] = {a4.x, a4.y, a4.z, a4.w};
            const float b[8] = {b4a.x, b4a.y, b4a.z, b4a.w,
                                b4b.x, b4b.y, b4b.z, b4b.w};
#pragma unroll
            for (int i = 0; i < 4; ++i)
#pragma unroll
                for (int j = 0; j < 8; ++j) acc[i][j] += a[i] * b[j];
        }
    }

    // ---- epilogue: + vec, tanh, store ----
#pragma unroll
    for (int i = 0; i < 4; ++i) {
        const int m = mBase + (tx << 2) + i;
        if (m < M) {
            const float* vrow = vec + (size_t)m * 256 + (ty << 3);
            float* orow = out + (size_t)m * 256 + (ty << 3);
            const float4 v0 = *reinterpret_cast<const float4*>(vrow);
            const float4 v1 = *reinterpret_cast<const float4*>(vrow + 4);
            float4 o0, o1;
            o0.x = tanhf(acc[i][0] + v0.x);
            o0.y = tanhf(acc[i][1] + v0.y);
            o0.z = tanhf(acc[i][2] + v0.z);
            o0.w = tanhf(acc[i][3] + v0.w);
            o1.x = tanhf(acc[i][4] + v1.x);
            o1.y = tanhf(acc[i][5] + v1.y);
            o1.z = tanhf(acc[i][6] + v1.z);
            o1.w = tanhf(acc[i][7] + v1.w);
            *reinterpret_cast<float4*>(orow) = o0;
            *reinterpret_cast<float4*>(orow + 4) = o1;
        }
    }
}

extern "C" void kernel_launch(void* const* d_in, const int* in_sizes, int n_in,
                              void* d_out, int out_size, void* d_ws, size_t ws_size,
                              hipStream_t stream) {
    const float* vectors = (const float*)d_in[0];
    const float* Wl = (const float*)d_in[1];
    const float* Wr = (const float*)d_in[2];
    // d_in[3] = branching (4), d_in[4] = n_levels (9) — fixed by setup, hardcoded.

    // workspace ping-pong: buf0 holds levels 7,5,3,1 (max 16384 rows),
    // buf1 holds levels 6,4,2 (max 4096 rows). Total 21 MB.
    float* buf0 = (float*)d_ws;
    float* buf1 = buf0 + (size_t)16384 * 256;

    // offsets[l] = (4^l - 1)/3
    size_t offsets[10];
    offsets[0] = 0;
    size_t sz = 1;
    for (int l = 0; l < 9; ++l) { offsets[l + 1] = offsets[l] + sz; sz *= 4; }

    const float* child = vectors + offsets[8] * 256;  // leaf level is vectors directly
    int flip = 0;
    for (int l = 7; l >= 0; --l) {
        const int M = 1 << (2 * l);  // 4^l parents
        float* dst = (l == 0) ? (float*)d_out : (flip ? buf1 : buf0);
        const float* vec = vectors + offsets[l] * 256;
        dim3 grid((M + BM - 1) / BM, 1), block(256);
        hipLaunchKernelGGL(cbt_level_kernel, grid, block, 0, stream,
                           child, Wl, Wr, vec, dst, M);
        child = dst;
        flip ^= 1;
    }
}

// Round 2
// 358.139 us; speedup vs baseline: 1.6657x; 1.6657x over previous
//
#include <hip/hip_runtime.h>
#include <math.h>

// CBTree contraction, B=4, L=9, d=256.
// Algebraic optimization: children combined BEFORE the matmul (GEMM linearity):
//   gL[p] = sum_b lc[b]*h[4p+b], gR[p] = sum_b rc[b]*h[4p+b]
//   h_new[p] = tanh( [gL|gR] @ [Wl|Wr].T + vec[p] )  -> M=n_par, K=512, N=256
// 4x fewer FLOPs than the reference.
//
// Round 2: tail levels (M<=4096) dominated round 1 (490 of 596 us) because
// per-block serial work was constant. Fix: BN=64 column-split for small levels
// (per-block VALU floor 3.4us), BN=128 for level 7 (1024 blocks = 4/CU,
// launch_bounds(256,4) -> 128 VGPRs for deeper ILP).

constexpr int BM = 32;
constexpr int BK = 32;

__device__ __forceinline__ float fast_tanh(float x) {
    // tanh(x) = sign(x) * (1 - e^{-2|x|}) / (1 + e^{-2|x|}); exp via v_exp_f32
    float ax = fabsf(x);
    float t = __builtin_amdgcn_exp2f(ax * -2.885390082f);  // 2*log2(e)
    float r = (1.0f - t) * __builtin_amdgcn_rcpf(1.0f + t);
    return copysignf(r, x);
}

// BN in {128, 64}. 256 threads. Micro-tile 4 x (BN/32) per thread.
// grid: (ceil(M/32), 256/BN)
template <int BN>
__global__ __launch_bounds__(256, 4) void cbt_gemm(
    const float* __restrict__ h,    // children, (4*M, 256)
    const float* __restrict__ Wl,   // (256,256) row-major
    const float* __restrict__ Wr,   // (256,256) row-major
    const float* __restrict__ vec,  // (M, 256)
    float* __restrict__ out,        // (M, 256)
    int M)
{
    constexpr int NPT = BN / 32;          // n-cols per thread AND B-rows staged per thread
    constexpr int ASTRIDE = BM + 4;       // 36 floats: 16B-aligned rows
    constexpr int BSTRIDE = BN + 4;       // 132 / 68 floats: 16B/8B-aligned

    __shared__ float As[BK][ASTRIDE];
    __shared__ float Bs[BK][BSTRIDE];

    const int tid = threadIdx.x;
    const int mBase = blockIdx.x * BM;
    const int nOff = blockIdx.y * BN;

    const int tx = tid & 7;    // m micro-rows: tx*4 .. tx*4+3
    const int ty = tid >> 3;   // n micro-cols: ty*NPT .. +NPT-1

    float acc[4][NPT];
#pragma unroll
    for (int i = 0; i < 4; ++i)
#pragma unroll
        for (int j = 0; j < NPT; ++j) acc[i][j] = 0.0f;

    constexpr float C23 = 2.0f / 3.0f;
    constexpr float C13 = 1.0f / 3.0f;

    // staging map: thread -> (row = tid>>3, 4-wide k chunk = (tid&7)*4)
    const int s_row = tid >> 3;        // 0..31
    const int s_kk  = (tid & 7) << 2;  // 0,4,...,28

    for (int k0 = 0; k0 < 512; k0 += BK) {
        // ---- global -> registers ----
        // A tile: fused child combine (lc=[1,2/3,1/3,0], rc=[0,1/3,2/3,1])
        float a_st[4] = {0.f, 0.f, 0.f, 0.f};
        const int m = mBase + s_row;
        if (m < M) {
            const float* hb = h + (size_t)m * 1024;
            if (k0 < 256) {
                const int k = k0 + s_kk;
                float4 v0 = *reinterpret_cast<const float4*>(hb + k);
                float4 v1 = *reinterpret_cast<const float4*>(hb + 256 + k);
                float4 v2 = *reinterpret_cast<const float4*>(hb + 512 + k);
                a_st[0] = v0.x + C23 * v1.x + C13 * v2.x;
                a_st[1] = v0.y + C23 * v1.y + C13 * v2.y;
                a_st[2] = v0.z + C23 * v1.z + C13 * v2.z;
                a_st[3] = v0.w + C23 * v1.w + C13 * v2.w;
            } else {
                const int k = (k0 - 256) + s_kk;
                float4 v1 = *reinterpret_cast<const float4*>(hb + 256 + k);
                float4 v2 = *reinterpret_cast<const float4*>(hb + 512 + k);
                float4 v3 = *reinterpret_cast<const float4*>(hb + 768 + k);
                a_st[0] = C13 * v1.x + C23 * v2.x + v3.x;
                a_st[1] = C13 * v1.y + C23 * v2.y + v3.y;
                a_st[2] = C13 * v1.z + C23 * v2.z + v3.z;
                a_st[3] = C13 * v1.w + C23 * v2.w + v3.w;
            }
        }

        // B tile: BN rows x 32 cols of [Wl|Wr]; NPT float4 per thread,
        // rows s_row + 32*i (coalesced 128B per 8 threads)
        const float* Wbase = (k0 < 256) ? (Wl + k0 + s_kk)
                                        : (Wr + (k0 - 256) + s_kk);
        float4 wv[NPT];
#pragma unroll
        for (int i = 0; i < NPT; ++i) {
            const int n = nOff + s_row + 32 * i;
            wv[i] = *reinterpret_cast<const float4*>(Wbase + (size_t)n * 256);
        }

        __syncthreads();  // previous iteration's compute done before overwrite

        // ---- registers -> LDS (transposed: [k][m] / [k][n]) ----
#pragma unroll
        for (int j = 0; j < 4; ++j) As[s_kk + j][s_row] = a_st[j];
#pragma unroll
        for (int i = 0; i < NPT; ++i) {
            float w_st[4] = {wv[i].x, wv[i].y, wv[i].z, wv[i].w};
#pragma unroll
            for (int j = 0; j < 4; ++j) Bs[s_kk + j][s_row + 32 * i] = w_st[j];
        }

        __syncthreads();

        // ---- compute: 32 k-steps, 4 x NPT micro-tile ----
#pragma unroll
        for (int kk = 0; kk < BK; ++kk) {
            const float4 a4 = *reinterpret_cast<const float4*>(&As[kk][tx << 2]);
            const float a[4] = {a4.x, a4.y, a4.z, a4.w};
            float b[NPT];
            if constexpr (NPT == 4) {
                const float4 b4 = *reinterpret_cast<const float4*>(&Bs[kk][ty * 4]);
                b[0] = b4.x; b[1] = b4.y; b[2] = b4.z; b[3] = b4.w;
            } else {
                const float2 b2 = *reinterpret_cast<const float2*>(&Bs[kk][ty * 2]);
                b[0] = b2.x; b[1] = b2.y;
            }
#pragma unroll
            for (int i = 0; i < 4; ++i)
#pragma unroll
                for (int j = 0; j < NPT; ++j) acc[i][j] += a[i] * b[j];
        }
    }

    // ---- epilogue: + vec, tanh, store ----
#pragma unroll
    for (int i = 0; i < 4; ++i) {
        const int m = mBase + (tx << 2) + i;
        if (m < M) {
            const float* vrow = vec + (size_t)m * 256 + nOff + ty * NPT;
            float* orow = out + (size_t)m * 256 + nOff + ty * NPT;
            if constexpr (NPT == 4) {
                const float4 v0 = *reinterpret_cast<const float4*>(vrow);
                float4 o;
                o.x = fast_tanh(acc[i][0] + v0.x);
                o.y = fast_tanh(acc[i][1] + v0.y);
                o.z = fast_tanh(acc[i][2] + v0.z);
                o.w = fast_tanh(acc[i][3] + v0.w);
                *reinterpret_cast<float4*>(orow) = o;
            } else {
                const float2 v0 = *reinterpret_cast<const float2*>(vrow);
                float2 o;
                o.x = fast_tanh(acc[i][0] + v0.x);
                o.y = fast_tanh(acc[i][1] + v0.y);
                *reinterpret_cast<float2*>(orow) = o;
            }
        }
    }
}

extern "C" void kernel_launch(void* const* d_in, const int* in_sizes, int n_in,
                              void* d_out, int out_size, void* d_ws, size_t ws_size,
                              hipStream_t stream) {
    const float* vectors = (const float*)d_in[0];
    const float* Wl = (const float*)d_in[1];
    const float* Wr = (const float*)d_in[2];
    // d_in[3] = branching (4), d_in[4] = n_levels (9) — fixed by setup.

    float* buf0 = (float*)d_ws;                       // levels 7,5,3,1 (<=16384 rows)
    float* buf1 = buf0 + (size_t)16384 * 256;         // levels 6,4,2

    size_t offsets[10];
    offsets[0] = 0;
    size_t sz = 1;
    for (int l = 0; l < 9; ++l) { offsets[l + 1] = offsets[l] + sz; sz *= 4; }

    const float* child = vectors + offsets[8] * 256;  // leaves = vectors directly
    int flip = 0;
    for (int l = 7; l >= 0; --l) {
        const int M = 1 << (2 * l);
        float* dst = (l == 0) ? (float*)d_out : (flip ? buf1 : buf0);
        const float* vec = vectors + offsets[l] * 256;
        const int mtiles = (M + BM - 1) / BM;
        if (l == 7) {
            dim3 grid(mtiles, 2), block(256);   // BN=128: 1024 blocks
            hipLaunchKernelGGL(cbt_gemm<128>, grid, block, 0, stream,
                               child, Wl, Wr, vec, dst, M);
        } else {
            dim3 grid(mtiles, 4), block(256);   // BN=64: 4x col-split for latency
            hipLaunchKernelGGL(cbt_gemm<64>, grid, block, 0, stream,
                               child, Wl, Wr, vec, dst, M);
        }
        child = dst;
        flip ^= 1;
    }
}

// Round 3
// 264.030 us; speedup vs baseline: 2.2594x; 1.3564x over previous
//
#include <hip/hip_runtime.h>
#include <math.h>

// CBTree contraction, B=4, L=9, d=256.
// g-combine before GEMM (linearity): per parent p,
//   gL[p]=sum_b lc[b]*h[4p+b], gR[p]=sum_b rc[b]*h[4p+b]
//   h_new[p] = tanh([gL|gR] @ [Wl|Wr].T + vec[p])   (M=n_par, K=512, N=256)
// Round 3: explicit register-prefetch pipeline (round-2 compiler didn't hoist
// loads: VGPR=36, VALUBusy 40%), 4x8 micro-tile for L7, wave-per-output
// kernel for tiny levels (kills the 16-iteration barrier chain).

__device__ __forceinline__ float fast_tanh(float x) {
    float ax = fabsf(x);
    float t = __builtin_amdgcn_exp2f(ax * -2.885390082f);  // 2*log2(e)
    float r = (1.0f - t) * __builtin_amdgcn_rcpf(1.0f + t);
    return copysignf(r, x);
}

// ---------------------------------------------------------------------------
// Kernel A: BM=64, BN=128, BK=32, 256 threads, micro 4x8. For L7 (M=16384).
// M % 64 == 0 assumed (no bounds checks).
// ---------------------------------------------------------------------------
__global__ __launch_bounds__(256, 2) void cbt_gemm_big(
    const float* __restrict__ h, const float* __restrict__ Wl,
    const float* __restrict__ Wr, const float* __restrict__ vec,
    float* __restrict__ out, int M)
{
    constexpr int AS = 68;    // A row stride (floats): 64+4, 16B-aligned rows
    constexpr int BS = 132;   // B row stride: 128+4
    __shared__ float As[32 * AS];
    __shared__ float Bs[32 * BS];

    const int tid = threadIdx.x;
    const int mBase = blockIdx.x * 64;
    const int nOff = blockIdx.y * 128;

    // staging maps
    const int a_m = tid >> 2;              // 0..63
    const int a_q = tid & 3;               // k-chunk: a_q*8 .. +7
    const int b_n = tid >> 1;              // 0..127
    const int b_k = (tid & 1) * 16;        // k: b_k .. b_k+15

    // compute maps (micro 4x8)
    const int tx = tid & 15;               // rows tx*4..+3
    const int ty = tid >> 4;               // cols ty*8..+7

    float acc[4][8];
#pragma unroll
    for (int i = 0; i < 4; ++i)
#pragma unroll
        for (int j = 0; j < 8; ++j) acc[i][j] = 0.0f;

    const float* hb = h + (size_t)(mBase + a_m) * 1024;

    // prefetch registers
    float4 ra0, ra1, rb0, rb1, rc0, rc1;   // A: 3 child rows x 2 float4
    float4 rw[4];                          // B: 4 float4
    float cw0, cw1, cw2;                   // combine coefs for current tile

    auto loadA = [&](int k0) {
        const bool isL = (k0 < 256);
        const float* base = hb + (isL ? 0 : 256) + (k0 & 255) + a_q * 8;
        cw0 = isL ? 1.0f : (1.0f / 3.0f);
        cw1 = 2.0f / 3.0f;
        cw2 = isL ? (1.0f / 3.0f) : 1.0f;
        ra0 = *reinterpret_cast<const float4*>(base);
        ra1 = *reinterpret_cast<const float4*>(base + 4);
        rb0 = *reinterpret_cast<const float4*>(base + 256);
        rb1 = *reinterpret_cast<const float4*>(base + 260);
        rc0 = *reinterpret_cast<const float4*>(base + 512);
        rc1 = *reinterpret_cast<const float4*>(base + 516);
    };
    auto loadB = [&](int k0) {
        const float* Wrow = ((k0 < 256) ? Wl : Wr) +
                            (size_t)(nOff + b_n) * 256 + (k0 & 255) + b_k;
#pragma unroll
        for (int j = 0; j < 4; ++j)
            rw[j] = *reinterpret_cast<const float4*>(Wrow + 4 * j);
    };

    loadA(0); loadB(0);

    for (int k0 = 0; k0 < 512; k0 += 32) {
        __syncthreads();
        // store A (combine) — scalar column writes into transposed layout
        {
            float g[8];
            g[0] = cw0 * ra0.x + cw1 * rb0.x + cw2 * rc0.x;
            g[1] = cw0 * ra0.y + cw1 * rb0.y + cw2 * rc0.y;
            g[2] = cw0 * ra0.z + cw1 * rb0.z + cw2 * rc0.z;
            g[3] = cw0 * ra0.w + cw1 * rb0.w + cw2 * rc0.w;
            g[4] = cw0 * ra1.x + cw1 * rb1.x + cw2 * rc1.x;
            g[5] = cw0 * ra1.y + cw1 * rb1.y + cw2 * rc1.y;
            g[6] = cw0 * ra1.z + cw1 * rb1.z + cw2 * rc1.z;
            g[7] = cw0 * ra1.w + cw1 * rb1.w + cw2 * rc1.w;
#pragma unroll
            for (int j = 0; j < 8; ++j) As[(a_q * 8 + j) * AS + a_m] = g[j];
        }
        // store B
        {
            const float w[16] = {rw[0].x, rw[0].y, rw[0].z, rw[0].w,
                                 rw[1].x, rw[1].y, rw[1].z, rw[1].w,
                                 rw[2].x, rw[2].y, rw[2].z, rw[2].w,
                                 rw[3].x, rw[3].y, rw[3].z, rw[3].w};
#pragma unroll
            for (int j = 0; j < 16; ++j) Bs[(b_k + j) * BS + b_n] = w[j];
        }
        __syncthreads();

        // prefetch next tile (latency hidden behind compute below)
        if (k0 + 32 < 512) { loadA(k0 + 32); loadB(k0 + 32); }

        // compute 32 k-steps
#pragma unroll
        for (int kk = 0; kk < 32; ++kk) {
            const float4 a4 = *reinterpret_cast<const float4*>(&As[kk * AS + tx * 4]);
            const float4 b0 = *reinterpret_cast<const float4*>(&Bs[kk * BS + ty * 8]);
            const float4 b1 = *reinterpret_cast<const float4*>(&Bs[kk * BS + ty * 8 + 4]);
            const float a[4] = {a4.x, a4.y, a4.z, a4.w};
            const float b[8] = {b0.x, b0.y, b0.z, b0.w, b1.x, b1.y, b1.z, b1.w};
#pragma unroll
            for (int i = 0; i < 4; ++i)
#pragma unroll
                for (int j = 0; j < 8; ++j) acc[i][j] += a[i] * b[j];
        }
    }

    // epilogue
#pragma unroll
    for (int i = 0; i < 4; ++i) {
        const int m = mBase + tx * 4 + i;
        const float* vrow = vec + (size_t)m * 256 + nOff + ty * 8;
        float* orow = out + (size_t)m * 256 + nOff + ty * 8;
        const float4 v0 = *reinterpret_cast<const float4*>(vrow);
        const float4 v1 = *reinterpret_cast<const float4*>(vrow + 4);
        float4 o0, o1;
        o0.x = fast_tanh(acc[i][0] + v0.x);
        o0.y = fast_tanh(acc[i][1] + v0.y);
        o0.z = fast_tanh(acc[i][2] + v0.z);
        o0.w = fast_tanh(acc[i][3] + v0.w);
        o1.x = fast_tanh(acc[i][4] + v1.x);
        o1.y = fast_tanh(acc[i][5] + v1.y);
        o1.z = fast_tanh(acc[i][6] + v1.z);
        o1.w = fast_tanh(acc[i][7] + v1.w);
        *reinterpret_cast<float4*>(orow) = o0;
        *reinterpret_cast<float4*>(orow + 4) = o1;
    }
}

// ---------------------------------------------------------------------------
// Kernel B: BM=32, BN=64, BK=64, 256 threads, micro 4x2. For L6/L5/L4.
// M % 32 == 0 assumed. 8 K-iterations, register-prefetch pipelined.
// ---------------------------------------------------------------------------
__global__ __launch_bounds__(256, 4) void cbt_gemm_mid(
    const float* __restrict__ h, const float* __restrict__ Wl,
    const float* __restrict__ Wr, const float* __restrict__ vec,
    float* __restrict__ out, int M)
{
    constexpr int AS = 36;   // 32+4
    constexpr int BS = 68;   // 64+4
    __shared__ float As[64 * AS];
    __shared__ float Bs[64 * BS];

    const int tid = threadIdx.x;
    const int mBase = blockIdx.x * 32;
    const int nOff = blockIdx.y * 64;

    const int a_m = tid >> 3;             // 0..31
    const int a_q = tid & 7;              // k-chunk a_q*8
    const int b_n = tid >> 2;             // 0..63
    const int b_k = (tid & 3) * 16;

    const int tx = tid & 7;               // rows tx*4
    const int ty = tid >> 3;              // cols ty*2

    float acc[4][2];
#pragma unroll
    for (int i = 0; i < 4; ++i) { acc[i][0] = 0.0f; acc[i][1] = 0.0f; }

    const float* hb = h + (size_t)(mBase + a_m) * 1024;

    float4 ra0, ra1, rb0, rb1, rc0, rc1;
    float4 rw[4];
    float cw0, cw1, cw2;

    auto loadA = [&](int k0) {
        const bool isL = (k0 < 256);
        const float* base = hb + (isL ? 0 : 256) + (k0 & 255) + a_q * 8;
        cw0 = isL ? 1.0f : (1.0f / 3.0f);
        cw1 = 2.0f / 3.0f;
        cw2 = isL ? (1.0f / 3.0f) : 1.0f;
        ra0 = *reinterpret_cast<const float4*>(base);
        ra1 = *reinterpret_cast<const float4*>(base + 4);
        rb0 = *reinterpret_cast<const float4*>(base + 256);
        rb1 = *reinterpret_cast<const float4*>(base + 260);
        rc0 = *reinterpret_cast<const float4*>(base + 512);
        rc1 = *reinterpret_cast<const float4*>(base + 516);
    };
    auto loadB = [&](int k0) {
        const float* Wrow = ((k0 < 256) ? Wl : Wr) +
                            (size_t)(nOff + b_n) * 256 + (k0 & 255) + b_k;
#pragma unroll
        for (int j = 0; j < 4; ++j)
            rw[j] = *reinterpret_cast<const float4*>(Wrow + 4 * j);
    };

    loadA(0); loadB(0);

    for (int k0 = 0; k0 < 512; k0 += 64) {
        __syncthreads();
        {
            float g[8];
            g[0] = cw0 * ra0.x + cw1 * rb0.x + cw2 * rc0.x;
            g[1] = cw0 * ra0.y + cw1 * rb0.y + cw2 * rc0.y;
            g[2] = cw0 * ra0.z + cw1 * rb0.z + cw2 * rc0.z;
            g[3] = cw0 * ra0.w + cw1 * rb0.w + cw2 * rc0.w;
            g[4] = cw0 * ra1.x + cw1 * rb1.x + cw2 * rc1.x;
            g[5] = cw0 * ra1.y + cw1 * rb1.y + cw2 * rc1.y;
            g[6] = cw0 * ra1.z + cw1 * rb1.z + cw2 * rc1.z;
            g[7] = cw0 * ra1.w + cw1 * rb1.w + cw2 * rc1.w;
#pragma unroll
            for (int j = 0; j < 8; ++j) As[(a_q * 8 + j) * AS + a_m] = g[j];
        }
        {
            const float w[16] = {rw[0].x, rw[0].y, rw[0].z, rw[0].w,
                                 rw[1].x, rw[1].y, rw[1].z, rw[1].w,
                                 rw[2].x, rw[2].y, rw[2].z, rw[2].w,
                                 rw[3].x, rw[3].y, rw[3].z, rw[3].w};
#pragma unroll
            for (int j = 0; j < 16; ++j) Bs[(b_k + j) * BS + b_n] = w[j];
        }
        __syncthreads();

        if (k0 + 64 < 512) { loadA(k0 + 64); loadB(k0 + 64); }

#pragma unroll
        for (int kk = 0; kk < 64; ++kk) {
            const float4 a4 = *reinterpret_cast<const float4*>(&As[kk * AS + tx * 4]);
            const float2 b2 = *reinterpret_cast<const float2*>(&Bs[kk * BS + ty * 2]);
            const float a[4] = {a4.x, a4.y, a4.z, a4.w};
#pragma unroll
            for (int i = 0; i < 4; ++i) {
                acc[i][0] += a[i] * b2.x;
                acc[i][1] += a[i] * b2.y;
            }
        }
    }

#pragma unroll
    for (int i = 0; i < 4; ++i) {
        const int m = mBase + tx * 4 + i;
        const float* vrow = vec + (size_t)m * 256 + nOff + ty * 2;
        float* orow = out + (size_t)m * 256 + nOff + ty * 2;
        const float2 v = *reinterpret_cast<const float2*>(vrow);
        float2 o;
        o.x = fast_tanh(acc[i][0] + v.x);
        o.y = fast_tanh(acc[i][1] + v.y);
        *reinterpret_cast<float2*>(orow) = o;
    }
}

// ---------------------------------------------------------------------------
// Kernel C: one wave per output element, for M <= 64 (L3..L0).
// Serial depth = one global-load round + 6-step butterfly. grid = M*64 blocks.
// ---------------------------------------------------------------------------
__global__ __launch_bounds__(256, 4) void cbt_small(
    const float* __restrict__ h, const float* __restrict__ Wl,
    const float* __restrict__ Wr, const float* __restrict__ vec,
    float* __restrict__ out)
{
    const int w = blockIdx.x * 4 + (threadIdx.x >> 6);
    const int lane = threadIdx.x & 63;
    const int m = w >> 8;
    const int n = w & 255;

    const float* hb = h + (size_t)m * 1024 + lane * 4;
    const float4 c0 = *reinterpret_cast<const float4*>(hb);
    const float4 c1 = *reinterpret_cast<const float4*>(hb + 256);
    const float4 c2 = *reinterpret_cast<const float4*>(hb + 512);
    const float4 c3 = *reinterpret_cast<const float4*>(hb + 768);
    const float4 wl = *reinterpret_cast<const float4*>(Wl + (size_t)n * 256 + lane * 4);
    const float4 wr = *reinterpret_cast<const float4*>(Wr + (size_t)n * 256 + lane * 4);

    constexpr float C23 = 2.0f / 3.0f;
    constexpr float C13 = 1.0f / 3.0f;
    float acc;
    {
        const float gl0 = c0.x + C23 * c1.x + C13 * c2.x;
        const float gl1 = c0.y + C23 * c1.y + C13 * c2.y;
        const float gl2 = c0.z + C23 * c1.z + C13 * c2.z;
        const float gl3 = c0.w + C23 * c1.w + C13 * c2.w;
        const float gr0 = C13 * c1.x + C23 * c2.x + c3.x;
        const float gr1 = C13 * c1.y + C23 * c2.y + c3.y;
        const float gr2 = C13 * c1.z + C23 * c2.z + c3.z;
        const float gr3 = C13 * c1.w + C23 * c2.w + c3.w;
        acc = gl0 * wl.x + gl1 * wl.y + gl2 * wl.z + gl3 * wl.w +
              gr0 * wr.x + gr1 * wr.y + gr2 * wr.z + gr3 * wr.w;
    }
#pragma unroll
    for (int off = 32; off >= 1; off >>= 1) acc += __shfl_xor(acc, off, 64);

    if (lane == 0)
        out[(size_t)m * 256 + n] = fast_tanh(acc + vec[(size_t)m * 256 + n]);
}

// ---------------------------------------------------------------------------
extern "C" void kernel_launch(void* const* d_in, const int* in_sizes, int n_in,
                              void* d_out, int out_size, void* d_ws, size_t ws_size,
                              hipStream_t stream) {
    const float* vectors = (const float*)d_in[0];
    const float* Wl = (const float*)d_in[1];
    const float* Wr = (const float*)d_in[2];

    float* buf0 = (float*)d_ws;                   // levels 7,5,3,1
    float* buf1 = buf0 + (size_t)16384 * 256;     // levels 6,4,2

    size_t offsets[10];
    offsets[0] = 0;
    size_t sz = 1;
    for (int l = 0; l < 9; ++l) { offsets[l + 1] = offsets[l] + sz; sz *= 4; }

    const float* child = vectors + offsets[8] * 256;  // leaves
    int flip = 0;
    for (int l = 7; l >= 0; --l) {
        const int M = 1 << (2 * l);
        float* dst = (l == 0) ? (float*)d_out : (flip ? buf1 : buf0);
        const float* vec = vectors + offsets[l] * 256;
        if (M >= 16384) {
            dim3 grid(M / 64, 2), block(256);
            hipLaunchKernelGGL(cbt_gemm_big, grid, block, 0, stream,
                               child, Wl, Wr, vec, dst, M);
        } else if (M >= 256) {
            dim3 grid(M / 32, 4), block(256);
            hipLaunchKernelGGL(cbt_gemm_mid, grid, block, 0, stream,
                               child, Wl, Wr, vec, dst, M);
        } else {
            dim3 grid(M * 64), block(256);
            hipLaunchKernelGGL(cbt_small, grid, block, 0, stream,
                               child, Wl, Wr, vec, dst);
        }
        child = dst;
        flip ^= 1;
    }
}

// Round 4
// 185.592 us; speedup vs baseline: 3.2143x; 1.4226x over previous
//
#include <hip/hip_runtime.h>
#include <math.h>

// CBTree contraction, B=4, L=9, d=256.
// g-combine before GEMM (linearity):
//   gL[p]=sum_b lc[b]*h[4p+b], gR[p]=sum_b rc[b]*h[4p+b]
//   h_new[p] = tanh([gL|gR] @ [Wl|Wr].T + vec[p])  (M=n_par, K=512, N=256)
// Round 4: bf16 MFMA for L7..L4 (round-3 fp32 kernel was LDS-port bound:
// 96 ds_read_b128/wave/iter vs 4096 FMA-cyc -> 38% VALUBusy ceiling).
// W pre-swizzled to B-fragment order (L1-resident, loaded per-wave with
// coalesced dwordx4 -> no LDS for B). A staged via LDS bf16 (2 reads/iter).
// Intermediates stored bf16 (error contracts through subsequent tanh levels;
// fp32 exact for L3..L0).

typedef __bf16 bf16x8 __attribute__((ext_vector_type(8)));
typedef __bf16 bf16x4 __attribute__((ext_vector_type(4)));
typedef float f32x4 __attribute__((ext_vector_type(4)));

__device__ __forceinline__ float fast_tanh(float x) {
    float ax = fabsf(x);
    float t = __builtin_amdgcn_exp2f(ax * -2.885390082f);  // 2*log2(e)
    float r = (1.0f - t) * __builtin_amdgcn_rcpf(1.0f + t);
    return copysignf(r, x);
}

// ---------------------------------------------------------------------------
// W swizzle: Wfrag holds [Wl|Wr] (N=256 x K=512) in MFMA B-fragment order.
// Fragment (J,T): 64 lanes x 8 bf16; lane L holds B[k=T*32+(L>>4)*8+j][n=J*16+(L&15)]
//   = Wcat[n][k].  Flat: Wfrag[(((J*16)+T)*64 + L)*8 + j]
// ---------------------------------------------------------------------------
__global__ __launch_bounds__(256) void cbt_wconv(
    const float* __restrict__ Wl, const float* __restrict__ Wr,
    __bf16* __restrict__ Wfrag)
{
    const int t = blockIdx.x * 256 + threadIdx.x;   // 0..16383
    const int L = t & 63;
    const int TJ = t >> 6;
    const int T = TJ & 15;
    const int J = TJ >> 4;
    const int n = J * 16 + (L & 15);
    const int k = T * 32 + (L >> 4) * 8;
    const float* src = (k < 256) ? (Wl + (size_t)n * 256 + k)
                                 : (Wr + (size_t)n * 256 + (k - 256));
    const float4 f0 = *reinterpret_cast<const float4*>(src);
    const float4 f1 = *reinterpret_cast<const float4*>(src + 4);
    bf16x8 o;
    o[0] = (__bf16)f0.x; o[1] = (__bf16)f0.y; o[2] = (__bf16)f0.z; o[3] = (__bf16)f0.w;
    o[4] = (__bf16)f1.x; o[5] = (__bf16)f1.y; o[6] = (__bf16)f1.z; o[7] = (__bf16)f1.w;
    *reinterpret_cast<bf16x8*>(Wfrag + (size_t)t * 8) = o;
}

// ---------------------------------------------------------------------------
// MFMA GEMM level kernel. Tile BM x 128, grid(M/BM, 2), 256 threads (4 waves).
// Wave-tile (BM/2) x 64: MI m-tiles x 4 n-tiles of 16x16, K-step 32.
// A (combined g, bf16) via LDS; B via coalesced register loads from Wfrag.
// CT = child dtype (float for leaf level, __bf16 for interior).
// ---------------------------------------------------------------------------
template <int BM, typename CT>
__global__ __launch_bounds__(256, 2) void cbt_mfma(
    const CT* __restrict__ h,          // (4*M, 256) children
    const __bf16* __restrict__ Wfrag,  // swizzled weights
    const float* __restrict__ vec,     // (M, 256)
    __bf16* __restrict__ out,          // (M, 256)
    int M)
{
    constexpr int MI = BM / 32;              // m-tiles per wave
    constexpr int SE = (BM == 64) ? 8 : 4;   // A elems staged per thread
    __shared__ __align__(16) __bf16 Alds[BM * 40];  // rows of 32 bf16, stride 40 (80B)

    const int tid = threadIdx.x;
    const int lane = tid & 63;
    const int w = tid >> 6;
    const int wr = w >> 1, wc = w & 1;
    const int mBase = blockIdx.x * BM;
    const int nOff = blockIdx.y * 128;

    f32x4 acc[MI][4] = {};

    // A staging geometry
    const int sm  = (BM == 64) ? (tid >> 2) : (tid >> 3);
    const int skq = (BM == 64) ? ((tid & 3) * 8) : ((tid & 7) * 4);
    const CT* hb = h + (size_t)(mBase + sm) * 1024;

    float ha[SE], hm[SE], hc[SE];
    float cA, cC;                 // combine coefs for the tile currently in regs
    auto load_h = [&](int k0) {
        const bool isL = (k0 < 256);
        cA = isL ? 1.0f : (1.0f / 3.0f);
        cC = isL ? (1.0f / 3.0f) : 1.0f;
        const CT* base = hb + (isL ? 0 : 256) + (k0 & 255) + skq;
        if constexpr (sizeof(CT) == 4) {            // fp32 children (SE==8)
            const float4 a0 = *reinterpret_cast<const float4*>(base);
            const float4 a1 = *reinterpret_cast<const float4*>(base + 4);
            const float4 b0 = *reinterpret_cast<const float4*>(base + 256);
            const float4 b1 = *reinterpret_cast<const float4*>(base + 260);
            const float4 c0 = *reinterpret_cast<const float4*>(base + 512);
            const float4 c1 = *reinterpret_cast<const float4*>(base + 516);
            ha[0]=a0.x; ha[1]=a0.y; ha[2]=a0.z; ha[3]=a0.w;
            ha[4]=a1.x; ha[5]=a1.y; ha[6]=a1.z; ha[7]=a1.w;
            hm[0]=b0.x; hm[1]=b0.y; hm[2]=b0.z; hm[3]=b0.w;
            hm[4]=b1.x; hm[5]=b1.y; hm[6]=b1.z; hm[7]=b1.w;
            hc[0]=c0.x; hc[1]=c0.y; hc[2]=c0.z; hc[3]=c0.w;
            hc[4]=c1.x; hc[5]=c1.y; hc[6]=c1.z; hc[7]=c1.w;
        } else {                                    // bf16 children (SE==4)
            const bf16x4 a = *reinterpret_cast<const bf16x4*>(base);
            const bf16x4 b = *reinterpret_cast<const bf16x4*>(base + 256);
            const bf16x4 c = *reinterpret_cast<const bf16x4*>(base + 512);
#pragma unroll
            for (int j = 0; j < 4; ++j) {
                ha[j] = (float)a[j]; hm[j] = (float)b[j]; hc[j] = (float)c[j];
            }
        }
    };

    auto store_A = [&]() {
        constexpr float CM = 2.0f / 3.0f;
        if constexpr (SE == 8) {
            bf16x8 g;
#pragma unroll
            for (int j = 0; j < 8; ++j)
                g[j] = (__bf16)(cA * ha[j] + CM * hm[j] + cC * hc[j]);
            *reinterpret_cast<bf16x8*>(&Alds[sm * 40 + skq]) = g;
        } else {
            bf16x4 g;
#pragma unroll
            for (int j = 0; j < 4; ++j)
                g[j] = (__bf16)(cA * ha[j] + CM * hm[j] + cC * hc[j]);
            *reinterpret_cast<bf16x4*>(&Alds[sm * 40 + skq]) = g;
        }
    };

    // B fragments: double-buffered registers, coalesced loads from Wfrag (L1-hot)
    bf16x8 bfr[2][4];
    const size_t J0 = (size_t)(nOff >> 4) + wc * 4;
    auto load_B = [&](int T, int buf) {
        const __bf16* p = Wfrag + ((J0 * 16 + T) * 64 + lane) * 8;
#pragma unroll
        for (int j = 0; j < 4; ++j)
            bfr[buf][j] = *reinterpret_cast<const bf16x8*>(p + (size_t)j * 8192);
    };

    load_h(0);
    load_B(0, 0);

    for (int T = 0; T < 16; ++T) {
        __syncthreads();              // all waves done with previous A tile
        store_A();
        __syncthreads();

        if (T < 15) {                 // prefetch next tile into regs
            load_B(T + 1, (T + 1) & 1);
            load_h((T + 1) * 32);
        }

        bf16x8 af[MI];
#pragma unroll
        for (int i = 0; i < MI; ++i)
            af[i] = *reinterpret_cast<const bf16x8*>(
                &Alds[((wr * MI + i) * 16 + (lane & 15)) * 40 + (lane >> 4) * 8]);

#pragma unroll
        for (int i = 0; i < MI; ++i)
#pragma unroll
            for (int j = 0; j < 4; ++j)
                acc[i][j] = __builtin_amdgcn_mfma_f32_16x16x32_bf16(
                    af[i], bfr[T & 1][j], acc[i][j], 0, 0, 0);
    }

    // epilogue: C/D layout col=lane&15, row=(lane>>4)*4+reg
    const int q = lane >> 4, n16 = lane & 15;
#pragma unroll
    for (int i = 0; i < MI; ++i) {
        const int mrow = mBase + (wr * MI + i) * 16 + q * 4;
#pragma unroll
        for (int j = 0; j < 4; ++j) {
            const int n = nOff + wc * 64 + j * 16 + n16;
#pragma unroll
            for (int r = 0; r < 4; ++r) {
                const size_t idx = (size_t)(mrow + r) * 256 + n;
                out[idx] = (__bf16)fast_tanh(acc[i][j][r] + vec[idx]);
            }
        }
    }
}

// ---------------------------------------------------------------------------
// Tiny levels (M <= 64): one wave per output element, fp32 math, bf16 children.
// grid = M*64 blocks of 256 (4 waves).
// ---------------------------------------------------------------------------
template <typename OT>
__global__ __launch_bounds__(256) void cbt_small(
    const __bf16* __restrict__ h, const float* __restrict__ Wl,
    const float* __restrict__ Wr, const float* __restrict__ vec,
    OT* __restrict__ out)
{
    const int w = blockIdx.x * 4 + (threadIdx.x >> 6);
    const int lane = threadIdx.x & 63;
    const int m = w >> 8;
    const int n = w & 255;

    const __bf16* hbp = h + (size_t)m * 1024 + lane * 4;
    const bf16x4 c0 = *reinterpret_cast<const bf16x4*>(hbp);
    const bf16x4 c1 = *reinterpret_cast<const bf16x4*>(hbp + 256);
    const bf16x4 c2 = *reinterpret_cast<const bf16x4*>(hbp + 512);
    const bf16x4 c3 = *reinterpret_cast<const bf16x4*>(hbp + 768);
    const float4 wl = *reinterpret_cast<const float4*>(Wl + (size_t)n * 256 + lane * 4);
    const float4 wr = *reinterpret_cast<const float4*>(Wr + (size_t)n * 256 + lane * 4);

    constexpr float C23 = 2.0f / 3.0f;
    constexpr float C13 = 1.0f / 3.0f;
    const float wlv[4] = {wl.x, wl.y, wl.z, wl.w};
    const float wrv[4] = {wr.x, wr.y, wr.z, wr.w};
    float acc = 0.0f;
#pragma unroll
    for (int j = 0; j < 4; ++j) {
        const float f0 = (float)c0[j], f1 = (float)c1[j];
        const float f2 = (float)c2[j], f3 = (float)c3[j];
        const float gl = f0 + C23 * f1 + C13 * f2;
        const float gr = C13 * f1 + C23 * f2 + f3;
        acc += gl * wlv[j] + gr * wrv[j];
    }
#pragma unroll
    for (int off = 32; off >= 1; off >>= 1) acc += __shfl_xor(acc, off, 64);

    if (lane == 0)
        out[(size_t)m * 256 + n] = (OT)fast_tanh(acc + vec[(size_t)m * 256 + n]);
}

// ---------------------------------------------------------------------------
extern "C" void kernel_launch(void* const* d_in, const int* in_sizes, int n_in,
                              void* d_out, int out_size, void* d_ws, size_t ws_size,
                              hipStream_t stream) {
    const float* vectors = (const float*)d_in[0];
    const float* Wl = (const float*)d_in[1];
    const float* Wr = (const float*)d_in[2];

    // ws layout (bf16): buf0 16384x256 (8MB), buf1 4096x256 (2MB), Wfrag 256KB
    __bf16* buf0 = (__bf16*)d_ws;
    __bf16* buf1 = buf0 + (size_t)16384 * 256;
    __bf16* Wfrag = buf1 + (size_t)4096 * 256;

    size_t offsets[10];
    offsets[0] = 0;
    size_t sz = 1;
    for (int l = 0; l < 9; ++l) { offsets[l + 1] = offsets[l] + sz; sz *= 4; }

    // weight swizzle (no dependency on h levels)
    hipLaunchKernelGGL(cbt_wconv, dim3(64), dim3(256), 0, stream, Wl, Wr, Wfrag);

    const float* leaf = vectors + offsets[8] * 256;

    // L7: fp32 leaves -> bf16 MFMA, BM=64: grid(256,2)=512 blocks
    hipLaunchKernelGGL((cbt_mfma<64, float>), dim3(256, 2), dim3(256), 0, stream,
                       leaf, Wfrag, vectors + offsets[7] * 256, buf0, 16384);
    // L6: BM=32: grid(128,2)=256 blocks
    hipLaunchKernelGGL((cbt_mfma<32, __bf16>), dim3(128, 2), dim3(256), 0, stream,
                       buf0, Wfrag, vectors + offsets[6] * 256, buf1, 4096);
    // L5: grid(32,2)=64 blocks
    hipLaunchKernelGGL((cbt_mfma<32, __bf16>), dim3(32, 2), dim3(256), 0, stream,
                       buf1, Wfrag, vectors + offsets[5] * 256, buf0, 1024);
    // L4: grid(8,2)=16 blocks
    hipLaunchKernelGGL((cbt_mfma<32, __bf16>), dim3(8, 2), dim3(256), 0, stream,
                       buf0, Wfrag, vectors + offsets[4] * 256, buf1, 256);
    // L3..L1: wave-per-output, bf16 out
    hipLaunchKernelGGL(cbt_small<__bf16>, dim3(64 * 64), dim3(256), 0, stream,
                       buf1, Wl, Wr, vectors + offsets[3] * 256, buf0);
    hipLaunchKernelGGL(cbt_small<__bf16>, dim3(16 * 64), dim3(256), 0, stream,
                       buf0, Wl, Wr, vectors + offsets[2] * 256, buf1);
    hipLaunchKernelGGL(cbt_small<__bf16>, dim3(4 * 64), dim3(256), 0, stream,
                       buf1, Wl, Wr, vectors + offsets[1] * 256, buf0);
    // L0: fp32 out to d_out
    hipLaunchKernelGGL(cbt_small<float>, dim3(1 * 64), dim3(256), 0, stream,
                       buf0, Wl, Wr, vectors + offsets[0] * 256, (float*)d_out);
}